// Round 12
// baseline (361.191 us; speedup 1.0000x reference)
//
#include <hip/hip_runtime.h>
#include <hip/hip_bf16.h>
#include <cstdint>

#define DIM 768
#define HEADS 12
#define DH 64
#define MLP_DIM 3072
#define ROWS 8192   // 8*1024
#define SEQ 1024
#define PPAD 72     // attn P scratch row stride (elements)

typedef __attribute__((ext_vector_type(8))) short bf16x8;
typedef __attribute__((ext_vector_type(4))) float f32x4;

typedef __attribute__((address_space(1))) void GV;
typedef __attribute__((address_space(3))) void SV;

__device__ inline void async16(const void* g, void* l) {
  __builtin_amdgcn_global_load_lds((GV*)(void*)g, (SV*)l, 16, 0, 0);
}

__device__ inline unsigned short f2b(float f) {
  union { float f; uint32_t u; } v; v.f = f;
  uint32_t u = v.u;
  return (unsigned short)((u + 0x7fffu + ((u >> 16) & 1u)) >> 16);
}

// fast GELU (erf via Abramowitz-Stegun 7.1.25, |eps|<=2.5e-5)
__device__ inline float gelu_f(float v) {
  float x = v * 0.70710678118654752f;
  float ax = fabsf(x);
  float t = 1.f / (1.f + 0.47047f * ax);
  float poly = t * (0.3480242f + t * (-0.0958798f + t * 0.7478556f));
  float erfv = 1.f - poly * __expf(-ax * ax);
  erfv = copysignf(erfv, x);
  return 0.5f * v * (1.f + erfv);
}

// ---------------- transpose fp32 [K][N] -> bf16 [N][K] ----------------
__global__ __launch_bounds__(256) void transpose_k(const float* __restrict__ in,
                                                   unsigned short* __restrict__ out,
                                                   int K, int N) {
  __shared__ float t[32][33];
  int tx = threadIdx.x & 31, ty = threadIdx.x >> 5;
  int bn = blockIdx.x * 32, bk = blockIdx.y * 32;
#pragma unroll
  for (int i = ty; i < 32; i += 8) t[i][tx] = in[(size_t)(bk + i) * N + bn + tx];
  __syncthreads();
#pragma unroll
  for (int i = ty; i < 32; i += 8) out[(size_t)(bn + i) * K + bk + tx] = f2b(t[tx][i]);
}

// ---------------- layernorm fp32 -> bf16, one wave per row, float4 I/O ------
__global__ __launch_bounds__(256) void ln_k(const float* __restrict__ x,
                                            const float* __restrict__ g,
                                            const float* __restrict__ b,
                                            unsigned short* __restrict__ h) {
  int wave = threadIdx.x >> 6, lane = threadIdx.x & 63;
  int row = blockIdx.x * 4 + wave;
  const float4* xr = (const float4*)(x + (size_t)row * DIM);
  float4 v[3];
  float s = 0.f;
#pragma unroll
  for (int j = 0; j < 3; ++j) {
    v[j] = xr[lane + j * 64];
    s += (v[j].x + v[j].y) + (v[j].z + v[j].w);
  }
#pragma unroll
  for (int m = 1; m < 64; m <<= 1) s += __shfl_xor(s, m);
  float mu = s * (1.f / DIM);
  float vs = 0.f;
#pragma unroll
  for (int j = 0; j < 3; ++j) {
    float d0 = v[j].x - mu, d1 = v[j].y - mu, d2 = v[j].z - mu, d3 = v[j].w - mu;
    vs += (d0 * d0 + d1 * d1) + (d2 * d2 + d3 * d3);
  }
#pragma unroll
  for (int m = 1; m < 64; m <<= 1) vs += __shfl_xor(vs, m);
  float rstd = rsqrtf(vs * (1.f / DIM) + 1e-5f);
  const float4* g4 = (const float4*)g;
  const float4* b4 = (const float4*)b;
  unsigned short* hr = h + (size_t)row * DIM;
#pragma unroll
  for (int j = 0; j < 3; ++j) {
    int i = lane + j * 64;
    float4 gg = g4[i], bb = b4[i];
    float y0 = (v[j].x - mu) * rstd * gg.x + bb.x;
    float y1 = (v[j].y - mu) * rstd * gg.y + bb.y;
    float y2 = (v[j].z - mu) * rstd * gg.z + bb.z;
    float y3 = (v[j].w - mu) * rstd * gg.w + bb.w;
    uint2 pk;
    pk.x = (uint32_t)f2b(y0) | ((uint32_t)f2b(y1) << 16);
    pk.y = (uint32_t)f2b(y2) | ((uint32_t)f2b(y3) << 16);
    *(uint2*)(hr + i * 4) = pk;
  }
}

// ---------------- m97-structure GEMM: TM=128 x BN, 256 thr, single-buf -----
// r9-proven optimum. BN=128 for QKV (grid 1152); BN=64 for the N=768 GEMMs
// (768 blocks, 3/CU) AND — r12 experiment — for MLP1 (grid 3072 = 12/CU,
// ~4-5 resident at 24KB LDS): deeper cross-block drain cover for short-K.
template <int MODE, int BN>
__global__ __launch_bounds__(256, 4) void gemm1b_k(
    const unsigned short* __restrict__ A, const unsigned short* __restrict__ Bt,
    int M, int N, int K,
    const float* __restrict__ bias, const float* __restrict__ resid,
    float* __restrict__ outf, unsigned short* __restrict__ outb,
    unsigned short* __restrict__ Qb, unsigned short* __restrict__ Kb,
    unsigned short* __restrict__ Vt) {
  constexpr int NI = BN / 32;                 // B-frags per wave (4 or 2)
  __shared__ __align__(16) unsigned short As[128 * 64];
  __shared__ __align__(16) unsigned short Bs[BN * 64];
  int tid = threadIdx.x;
  int wave = tid >> 6, lane = tid & 63, lrow = lane & 15, qd = lane >> 4;
  int ntn = N / BN;

  int nwg = gridDim.x;
  int wg = blockIdx.x;
  if ((nwg & 7) == 0) wg = (wg & 7) * (nwg >> 3) + (wg >> 3);

  int bm = (wg / ntn) << 7;
  int bn = (wg % ntn) * BN;
  int wm = (wave >> 1) * 64;
  int wn = (wave & 1) * (BN / 2);

  f32x4 acc[4][NI];
#pragma unroll
  for (int i = 0; i < 4; ++i)
#pragma unroll
    for (int j = 0; j < NI; ++j) acc[i][j] = (f32x4){0.f, 0.f, 0.f, 0.f};

  int srow = tid >> 3;
  int c = (tid & 7) ^ (srow & 7);
  const char* gA = (const char*)(A + (size_t)(bm + srow) * K) + c * 16;
  const char* gB = (const char*)(Bt + (size_t)(bn + srow) * K) + c * 16;
  size_t rstep = (size_t)32 * K * 2;

  auto stage = [&](int kt) {
    size_t ko = (size_t)kt * 128;
    char* lA = (char*)As + tid * 16;
    char* lB = (char*)Bs + tid * 16;
#pragma unroll
    for (int j = 0; j < 4; ++j) async16(gA + ko + j * rstep, lA + j * 4096);
#pragma unroll
    for (int j = 0; j < BN / 32; ++j) async16(gB + ko + j * rstep, lB + j * 4096);
  };

  int nk = K >> 6;
  stage(0);
  for (int kt = 0; kt < nk; ++kt) {
    __syncthreads();   // drains own stage loads before barrier -> tile ready
#pragma unroll
    for (int s = 0; s < 2; ++s) {
      int q = s * 4 + qd;
      bf16x8 af[4], bfr[NI];
#pragma unroll
      for (int i = 0; i < 4; ++i) {
        int r = wm + i * 16 + lrow;
        af[i] = *(const bf16x8*)(As + r * 64 + ((q ^ (r & 7)) << 3));
      }
#pragma unroll
      for (int i = 0; i < NI; ++i) {
        int r = wn + i * 16 + lrow;
        bfr[i] = *(const bf16x8*)(Bs + r * 64 + ((q ^ (r & 7)) << 3));
      }
#pragma unroll
      for (int mi = 0; mi < 4; ++mi)
#pragma unroll
        for (int ni = 0; ni < NI; ++ni)
          acc[mi][ni] = __builtin_amdgcn_mfma_f32_16x16x32_bf16(af[mi], bfr[ni], acc[mi][ni], 0, 0, 0);
    }
    __syncthreads();   // all waves done reading As/Bs -> safe to overwrite
    if (kt + 1 < nk) stage(kt + 1);
  }

#pragma unroll
  for (int mi = 0; mi < 4; ++mi)
#pragma unroll
    for (int ni = 0; ni < NI; ++ni)
#pragma unroll
      for (int r = 0; r < 4; ++r) {
        int row = bm + wm + mi * 16 + qd * 4 + r;
        int col = bn + wn + ni * 16 + lrow;
        float v = acc[mi][ni][r];
        if (MODE == 0) {
          int which = col / 768;
          int rem = col - which * 768;
          int hh = rem >> 6, dh = rem & 63;
          int bb = row >> 10, n = row & 1023;
          size_t bh = (size_t)(bb * HEADS + hh);
          if (which == 0) {
            Qb[(bh * SEQ + n) * DH + dh] = f2b(v * 0.125f);
          } else if (which == 1) {
            Kb[(bh * SEQ + n) * DH + (((dh >> 3) ^ (n & 7)) << 3) + (dh & 7)] = f2b(v);
          } else {
            Vt[(bh * DH + dh) * SEQ + (n & ~63) +
               ((((n >> 3) & 7) ^ (dh & 7)) << 3) + (n & 7)] = f2b(v);
          }
        } else if (MODE == 1) {
          v += bias[col] + resid[(size_t)row * 768 + col];
          outf[(size_t)row * 768 + col] = v;
        } else {
          v += bias[col];
          outb[(size_t)row * MLP_DIM + col] = f2b(gelu_f(v));
        }
      }
}

// ---------------- flash attention v2 (+ T5 setprio around MFMA clusters) ---
__global__ __launch_bounds__(256, 3) void attn_k(const unsigned short* __restrict__ Qb,
                                                 const unsigned short* __restrict__ Kb,
                                                 const unsigned short* __restrict__ Vt,
                                                 unsigned short* __restrict__ o) {
  __shared__ __align__(16) unsigned short Ks[2][64 * 64];
  __shared__ __align__(16) unsigned short Vs[2][64 * 64];
  __shared__ __align__(16) unsigned short Pa[4][32 * PPAD];
  int tid = threadIdx.x;
  int wave = tid >> 6, lane = tid & 63;
  int lrow = lane & 15, qd = lane >> 4;
  int bh = blockIdx.x % 96;
  int qt = blockIdx.x / 96;
  int b = bh / HEADS, hh = bh % HEADS;
  const unsigned short* Qh = Qb + (size_t)bh * SEQ * DH;
  const char* Kh = (const char*)(Kb + (size_t)bh * SEQ * DH);
  const char* Vh = (const char*)(Vt + (size_t)bh * DH * SEQ);
  int qw = qt * 128 + wave * 32;

  bf16x8 qf[2][2];
#pragma unroll
  for (int qs = 0; qs < 2; ++qs)
#pragma unroll
    for (int hf = 0; hf < 2; ++hf)
      qf[qs][hf] = *(const bf16x8*)(Qh + (qw + qs * 16 + lrow) * DH + hf * 32 + qd * 8);

  f32x4 oacc[2][4];
#pragma unroll
  for (int qs = 0; qs < 2; ++qs)
#pragma unroll
    for (int d = 0; d < 4; ++d) oacc[qs][d] = (f32x4){0.f, 0.f, 0.f, 0.f};
  float li[2] = {0.f, 0.f};
  unsigned short* Pw = Pa[wave];

  auto stage = [&](int t, int buf) {
    const char* kbase = Kh + (size_t)t * 8192;
    char* kd = (char*)Ks[buf];
    async16(kbase + tid * 16, kd + tid * 16);
    async16(kbase + 4096 + tid * 16, kd + 4096 + tid * 16);
    const char* vbase = Vh + (size_t)t * 128;
    char* vd = (char*)Vs[buf];
    async16(vbase + (size_t)(tid >> 3) * 2048 + (tid & 7) * 16, vd + tid * 16);
    async16(vbase + (size_t)((tid >> 3) + 32) * 2048 + (tid & 7) * 16, vd + 4096 + tid * 16);
  };

  stage(0, 0);
  for (int t = 0; t < 16; ++t) {
    asm volatile("s_waitcnt vmcnt(0)" ::: "memory");
    __syncthreads();
    if (t < 15) stage(t + 1, (t + 1) & 1);
    const unsigned short* Kst = Ks[t & 1];
    const unsigned short* Vst = Vs[t & 1];

    f32x4 st[4][2];
    __builtin_amdgcn_s_setprio(1);
#pragma unroll
    for (int kt = 0; kt < 4; ++kt) {
      int krow = kt * 16 + lrow;
      int ksw = krow & 7;
      const unsigned short* Kr = Kst + krow * 64;
      bf16x8 k0 = *(const bf16x8*)(Kr + ((qd ^ ksw) << 3));
      bf16x8 k1 = *(const bf16x8*)(Kr + (((qd + 4) ^ ksw) << 3));
#pragma unroll
      for (int qs = 0; qs < 2; ++qs) {
        f32x4 z = (f32x4){0.f, 0.f, 0.f, 0.f};
        z = __builtin_amdgcn_mfma_f32_16x16x32_bf16(k0, qf[qs][0], z, 0, 0, 0);
        z = __builtin_amdgcn_mfma_f32_16x16x32_bf16(k1, qf[qs][1], z, 0, 0, 0);
        st[kt][qs] = z;
      }
    }
    __builtin_amdgcn_s_setprio(0);

#pragma unroll
    for (int kt = 0; kt < 4; ++kt)
#pragma unroll
      for (int qs = 0; qs < 2; ++qs) {
        float p0 = __expf(st[kt][qs][0]);
        float p1 = __expf(st[kt][qs][1]);
        float p2 = __expf(st[kt][qs][2]);
        float p3 = __expf(st[kt][qs][3]);
        li[qs] += (p0 + p1) + (p2 + p3);
        uint2 pk;
        pk.x = (uint32_t)f2b(p0) | ((uint32_t)f2b(p1) << 16);
        pk.y = (uint32_t)f2b(p2) | ((uint32_t)f2b(p3) << 16);
        *(uint2*)(Pw + (qs * 16 + lrow) * PPAD + kt * 16 + qd * 4) = pk;
      }
    asm volatile("s_waitcnt lgkmcnt(0)" ::: "memory");

    bf16x8 ap[2][2];
#pragma unroll
    for (int qs = 0; qs < 2; ++qs)
#pragma unroll
      for (int kh = 0; kh < 2; ++kh)
        ap[qs][kh] = *(const bf16x8*)(Pw + (qs * 16 + lrow) * PPAD + kh * 32 + qd * 8);

    __builtin_amdgcn_s_setprio(1);
#pragma unroll
    for (int ds = 0; ds < 4; ++ds) {
      int vrow = ds * 16 + lrow;
      int vsw = vrow & 7;
      const unsigned short* Vr = Vst + vrow * 64;
      bf16x8 v0 = *(const bf16x8*)(Vr + ((qd ^ vsw) << 3));
      bf16x8 v1 = *(const bf16x8*)(Vr + (((4 + qd) ^ vsw) << 3));
#pragma unroll
      for (int qs = 0; qs < 2; ++qs) {
        oacc[qs][ds] = __builtin_amdgcn_mfma_f32_16x16x32_bf16(ap[qs][0], v0, oacc[qs][ds], 0, 0, 0);
        oacc[qs][ds] = __builtin_amdgcn_mfma_f32_16x16x32_bf16(ap[qs][1], v1, oacc[qs][ds], 0, 0, 0);
      }
    }
    __builtin_amdgcn_s_setprio(0);
  }

#pragma unroll
  for (int qs = 0; qs < 2; ++qs) {
    li[qs] += __shfl_xor(li[qs], 16);
    li[qs] += __shfl_xor(li[qs], 32);
  }

#pragma unroll
  for (int qs = 0; qs < 2; ++qs)
#pragma unroll
    for (int r = 0; r < 4; ++r) {
      float inv = 1.f / __shfl(li[qs], qd * 4 + r);
      int n = qw + qs * 16 + qd * 4 + r;
#pragma unroll
      for (int ds = 0; ds < 4; ++ds) {
        int dh = ds * 16 + lrow;
        o[((size_t)(b * SEQ + n)) * DIM + hh * DH + dh] = f2b(oacc[qs][ds][r] * inv);
      }
    }
}

extern "C" void kernel_launch(void* const* d_in, const int* in_sizes, int n_in,
                              void* d_out, int out_size, void* d_ws, size_t ws_size,
                              hipStream_t stream) {
  const float* x     = (const float*)d_in[0];
  const float* ln1_g = (const float*)d_in[1];
  const float* ln1_b = (const float*)d_in[2];
  const float* w_qkv = (const float*)d_in[3];
  const float* w_out = (const float*)d_in[4];
  const float* b_out = (const float*)d_in[5];
  const float* ln2_g = (const float*)d_in[6];
  const float* ln2_b = (const float*)d_in[7];
  const float* w1    = (const float*)d_in[8];
  const float* b1    = (const float*)d_in[9];
  const float* w2    = (const float*)d_in[10];
  const float* b2    = (const float*)d_in[11];

  char* ws = (char*)d_ws;
  unsigned short* wqkvT = (unsigned short*)(ws + 0);
  unsigned short* woutT = (unsigned short*)(ws + 3538944);
  unsigned short* w1T   = (unsigned short*)(ws + 4718592);
  unsigned short* w2T   = (unsigned short*)(ws + 9437184);
  float*          x2    = (float*)(ws + 14155776);
  unsigned short* h     = (unsigned short*)(ws + 39321600);
  char* big = ws + 51904512;
  unsigned short* Qb = (unsigned short*)(big);
  unsigned short* Kb = (unsigned short*)(big + 12582912);
  unsigned short* Vt = (unsigned short*)(big + 25165824);
  unsigned short* ob = (unsigned short*)(big + 37748736);
  unsigned short* am = (unsigned short*)(big);

  transpose_k<<<dim3(72, 24), 256, 0, stream>>>(w_qkv, wqkvT, 768, 2304);
  transpose_k<<<dim3(24, 24), 256, 0, stream>>>(w_out, woutT, 768, 768);
  transpose_k<<<dim3(96, 24), 256, 0, stream>>>(w1, w1T, 768, 3072);
  transpose_k<<<dim3(24, 96), 256, 0, stream>>>(w2, w2T, 3072, 768);

  ln_k<<<2048, 256, 0, stream>>>(x, ln1_g, ln1_b, h);
  gemm1b_k<0, 128><<<64 * 18, 256, 0, stream>>>(h, wqkvT, ROWS, 2304, 768,
                                                nullptr, nullptr, nullptr, nullptr, Qb, Kb, Vt);
  attn_k<<<768, 256, 0, stream>>>(Qb, Kb, Vt, ob);
  gemm1b_k<1, 64><<<64 * 12, 256, 0, stream>>>(ob, woutT, ROWS, 768, 768,
                                               b_out, x, x2, nullptr, nullptr, nullptr, nullptr);
  ln_k<<<2048, 256, 0, stream>>>(x2, ln2_g, ln2_b, h);
  gemm1b_k<2, 64><<<64 * 48, 256, 0, stream>>>(h, w1T, ROWS, 3072, 768,
                                               b1, nullptr, nullptr, am, nullptr, nullptr, nullptr);
  gemm1b_k<1, 64><<<64 * 12, 256, 0, stream>>>(am, w2T, ROWS, 768, 3072,
                                               b2, x2, (float*)d_out, nullptr, nullptr, nullptr, nullptr);
}

// Round 13
// 338.349 us; speedup vs baseline: 1.0675x; 1.0675x over previous
//
#include <hip/hip_runtime.h>
#include <hip/hip_bf16.h>
#include <cstdint>

#define DIM 768
#define HEADS 12
#define DH 64
#define MLP_DIM 3072
#define ROWS 8192   // 8*1024
#define SEQ 1024
#define PPAD 72     // attn P scratch row stride (elements)

typedef __attribute__((ext_vector_type(8))) short bf16x8;
typedef __attribute__((ext_vector_type(4))) float f32x4;

typedef __attribute__((address_space(1))) void GV;
typedef __attribute__((address_space(3))) void SV;

__device__ inline void async16(const void* g, void* l) {
  __builtin_amdgcn_global_load_lds((GV*)(void*)g, (SV*)l, 16, 0, 0);
}

__device__ inline unsigned short f2b(float f) {
  union { float f; uint32_t u; } v; v.f = f;
  uint32_t u = v.u;
  return (unsigned short)((u + 0x7fffu + ((u >> 16) & 1u)) >> 16);
}

// fast GELU (erf via Abramowitz-Stegun 7.1.25, |eps|<=2.5e-5)
__device__ inline float gelu_f(float v) {
  float x = v * 0.70710678118654752f;
  float ax = fabsf(x);
  float t = 1.f / (1.f + 0.47047f * ax);
  float poly = t * (0.3480242f + t * (-0.0958798f + t * 0.7478556f));
  float erfv = 1.f - poly * __expf(-ax * ax);
  erfv = copysignf(erfv, x);
  return 0.5f * v * (1.f + erfv);
}

// ---------------- layernorm row quad (one wave -> one row) -----------------
__device__ inline void ln_row(const float* __restrict__ x,
                              const float* __restrict__ g,
                              const float* __restrict__ b,
                              unsigned short* __restrict__ h,
                              int row, int lane) {
  const float4* xr = (const float4*)(x + (size_t)row * DIM);
  float4 v[3];
  float s = 0.f;
#pragma unroll
  for (int j = 0; j < 3; ++j) {
    v[j] = xr[lane + j * 64];
    s += (v[j].x + v[j].y) + (v[j].z + v[j].w);
  }
#pragma unroll
  for (int m = 1; m < 64; m <<= 1) s += __shfl_xor(s, m);
  float mu = s * (1.f / DIM);
  float vs = 0.f;
#pragma unroll
  for (int j = 0; j < 3; ++j) {
    float d0 = v[j].x - mu, d1 = v[j].y - mu, d2 = v[j].z - mu, d3 = v[j].w - mu;
    vs += (d0 * d0 + d1 * d1) + (d2 * d2 + d3 * d3);
  }
#pragma unroll
  for (int m = 1; m < 64; m <<= 1) vs += __shfl_xor(vs, m);
  float rstd = rsqrtf(vs * (1.f / DIM) + 1e-5f);
  const float4* g4 = (const float4*)g;
  const float4* b4 = (const float4*)b;
  unsigned short* hr = h + (size_t)row * DIM;
#pragma unroll
  for (int j = 0; j < 3; ++j) {
    int i = lane + j * 64;
    float4 gg = g4[i], bb = b4[i];
    float y0 = (v[j].x - mu) * rstd * gg.x + bb.x;
    float y1 = (v[j].y - mu) * rstd * gg.y + bb.y;
    float y2 = (v[j].z - mu) * rstd * gg.z + bb.z;
    float y3 = (v[j].w - mu) * rstd * gg.w + bb.w;
    uint2 pk;
    pk.x = (uint32_t)f2b(y0) | ((uint32_t)f2b(y1) << 16);
    pk.y = (uint32_t)f2b(y2) | ((uint32_t)f2b(y3) << 16);
    *(uint2*)(hr + i * 4) = pk;
  }
}

// ---------------- standalone layernorm (ln2) -------------------------------
__global__ __launch_bounds__(256) void ln_k(const float* __restrict__ x,
                                            const float* __restrict__ g,
                                            const float* __restrict__ b,
                                            unsigned short* __restrict__ h) {
  int wave = threadIdx.x >> 6, lane = threadIdx.x & 63;
  ln_row(x, g, b, h, blockIdx.x * 4 + wave, lane);
}

// ---------------- fused prep: 4 weight transposes + ln1 in ONE launch ------
// All five jobs depend only on kernel inputs (weights, x) -> fully
// independent; whole-block branching on blockIdx ranges (no divergence).
// r12 PM: ~75us of the wall is inter-dispatch overhead across 11 kernels;
// this cuts the launch count 11 -> 7.
__global__ __launch_bounds__(256) void prep_k(
    const float* __restrict__ w_qkv, const float* __restrict__ w_out,
    const float* __restrict__ w1, const float* __restrict__ w2,
    const float* __restrict__ x,
    const float* __restrict__ ln1_g, const float* __restrict__ ln1_b,
    unsigned short* __restrict__ wqkvT, unsigned short* __restrict__ woutT,
    unsigned short* __restrict__ w1T, unsigned short* __restrict__ w2T,
    unsigned short* __restrict__ h) {
  __shared__ float t[32][33];
  int id = blockIdx.x;
  if (id < 2048) {                     // ln1: 2048 blocks x 4 rows
    int wave = threadIdx.x >> 6, lane = threadIdx.x & 63;
    ln_row(x, ln1_g, ln1_b, h, id * 4 + wave, lane);
    return;
  }
  id -= 2048;
  const float* in; unsigned short* out; int K, N, bx, by;
  if (id < 1728)        { in = w_qkv; out = wqkvT; K = 768;  N = 2304; bx = id % 72; by = id / 72; }
  else if (id < 2304)   { id -= 1728; in = w_out; out = woutT; K = 768;  N = 768;  bx = id % 24; by = id / 24; }
  else if (id < 4608)   { id -= 2304; in = w1;    out = w1T;   K = 768;  N = 3072; bx = id % 96; by = id / 96; }
  else                  { id -= 4608; in = w2;    out = w2T;   K = 3072; N = 768;  bx = id % 24; by = id / 24; }
  int tx = threadIdx.x & 31, ty = threadIdx.x >> 5;
  int bn = bx * 32, bk = by * 32;
#pragma unroll
  for (int i = ty; i < 32; i += 8) t[i][tx] = in[(size_t)(bk + i) * N + bn + tx];
  __syncthreads();
#pragma unroll
  for (int i = ty; i < 32; i += 8) out[(size_t)(bn + i) * K + bk + tx] = f2b(t[tx][i]);
}

// ---------------- m97-structure GEMM: TM=128 x BN, 256 thr, single-buf -----
// r9-proven optimum: BN=128 for QKV (1152 blocks) and MLP1 (1536);
// BN=64 for the N=768 GEMMs (768 blocks, 3/CU).
template <int MODE, int BN>
__global__ __launch_bounds__(256, 4) void gemm1b_k(
    const unsigned short* __restrict__ A, const unsigned short* __restrict__ Bt,
    int M, int N, int K,
    const float* __restrict__ bias, const float* __restrict__ resid,
    float* __restrict__ outf, unsigned short* __restrict__ outb,
    unsigned short* __restrict__ Qb, unsigned short* __restrict__ Kb,
    unsigned short* __restrict__ Vt) {
  constexpr int NI = BN / 32;                 // B-frags per wave (4 or 2)
  __shared__ __align__(16) unsigned short As[128 * 64];
  __shared__ __align__(16) unsigned short Bs[BN * 64];
  int tid = threadIdx.x;
  int wave = tid >> 6, lane = tid & 63, lrow = lane & 15, qd = lane >> 4;
  int ntn = N / BN;

  int nwg = gridDim.x;
  int wg = blockIdx.x;
  if ((nwg & 7) == 0) wg = (wg & 7) * (nwg >> 3) + (wg >> 3);

  int bm = (wg / ntn) << 7;
  int bn = (wg % ntn) * BN;
  int wm = (wave >> 1) * 64;
  int wn = (wave & 1) * (BN / 2);

  f32x4 acc[4][NI];
#pragma unroll
  for (int i = 0; i < 4; ++i)
#pragma unroll
    for (int j = 0; j < NI; ++j) acc[i][j] = (f32x4){0.f, 0.f, 0.f, 0.f};

  int srow = tid >> 3;
  int c = (tid & 7) ^ (srow & 7);
  const char* gA = (const char*)(A + (size_t)(bm + srow) * K) + c * 16;
  const char* gB = (const char*)(Bt + (size_t)(bn + srow) * K) + c * 16;
  size_t rstep = (size_t)32 * K * 2;

  auto stage = [&](int kt) {
    size_t ko = (size_t)kt * 128;
    char* lA = (char*)As + tid * 16;
    char* lB = (char*)Bs + tid * 16;
#pragma unroll
    for (int j = 0; j < 4; ++j) async16(gA + ko + j * rstep, lA + j * 4096);
#pragma unroll
    for (int j = 0; j < BN / 32; ++j) async16(gB + ko + j * rstep, lB + j * 4096);
  };

  int nk = K >> 6;
  stage(0);
  for (int kt = 0; kt < nk; ++kt) {
    __syncthreads();   // drains own stage loads before barrier -> tile ready
#pragma unroll
    for (int s = 0; s < 2; ++s) {
      int q = s * 4 + qd;
      bf16x8 af[4], bfr[NI];
#pragma unroll
      for (int i = 0; i < 4; ++i) {
        int r = wm + i * 16 + lrow;
        af[i] = *(const bf16x8*)(As + r * 64 + ((q ^ (r & 7)) << 3));
      }
#pragma unroll
      for (int i = 0; i < NI; ++i) {
        int r = wn + i * 16 + lrow;
        bfr[i] = *(const bf16x8*)(Bs + r * 64 + ((q ^ (r & 7)) << 3));
      }
#pragma unroll
      for (int mi = 0; mi < 4; ++mi)
#pragma unroll
        for (int ni = 0; ni < NI; ++ni)
          acc[mi][ni] = __builtin_amdgcn_mfma_f32_16x16x32_bf16(af[mi], bfr[ni], acc[mi][ni], 0, 0, 0);
    }
    __syncthreads();   // all waves done reading As/Bs -> safe to overwrite
    if (kt + 1 < nk) stage(kt + 1);
  }

#pragma unroll
  for (int mi = 0; mi < 4; ++mi)
#pragma unroll
    for (int ni = 0; ni < NI; ++ni)
#pragma unroll
      for (int r = 0; r < 4; ++r) {
        int row = bm + wm + mi * 16 + qd * 4 + r;
        int col = bn + wn + ni * 16 + lrow;
        float v = acc[mi][ni][r];
        if (MODE == 0) {
          int which = col / 768;
          int rem = col - which * 768;
          int hh = rem >> 6, dh = rem & 63;
          int bb = row >> 10, n = row & 1023;
          size_t bh = (size_t)(bb * HEADS + hh);
          if (which == 0) {
            Qb[(bh * SEQ + n) * DH + dh] = f2b(v * 0.125f);
          } else if (which == 1) {
            Kb[(bh * SEQ + n) * DH + (((dh >> 3) ^ (n & 7)) << 3) + (dh & 7)] = f2b(v);
          } else {
            Vt[(bh * DH + dh) * SEQ + (n & ~63) +
               ((((n >> 3) & 7) ^ (dh & 7)) << 3) + (n & 7)] = f2b(v);
          }
        } else if (MODE == 1) {
          v += bias[col] + resid[(size_t)row * 768 + col];
          outf[(size_t)row * 768 + col] = v;
        } else {
          v += bias[col];
          outb[(size_t)row * MLP_DIM + col] = f2b(gelu_f(v));
        }
      }
}

// ---------------- flash attention v2 (r9-exact, no setprio) ----------------
__global__ __launch_bounds__(256, 3) void attn_k(const unsigned short* __restrict__ Qb,
                                                 const unsigned short* __restrict__ Kb,
                                                 const unsigned short* __restrict__ Vt,
                                                 unsigned short* __restrict__ o) {
  __shared__ __align__(16) unsigned short Ks[2][64 * 64];
  __shared__ __align__(16) unsigned short Vs[2][64 * 64];
  __shared__ __align__(16) unsigned short Pa[4][32 * PPAD];
  int tid = threadIdx.x;
  int wave = tid >> 6, lane = tid & 63;
  int lrow = lane & 15, qd = lane >> 4;
  int bh = blockIdx.x % 96;
  int qt = blockIdx.x / 96;
  int b = bh / HEADS, hh = bh % HEADS;
  const unsigned short* Qh = Qb + (size_t)bh * SEQ * DH;
  const char* Kh = (const char*)(Kb + (size_t)bh * SEQ * DH);
  const char* Vh = (const char*)(Vt + (size_t)bh * DH * SEQ);
  int qw = qt * 128 + wave * 32;

  bf16x8 qf[2][2];
#pragma unroll
  for (int qs = 0; qs < 2; ++qs)
#pragma unroll
    for (int hf = 0; hf < 2; ++hf)
      qf[qs][hf] = *(const bf16x8*)(Qh + (qw + qs * 16 + lrow) * DH + hf * 32 + qd * 8);

  f32x4 oacc[2][4];
#pragma unroll
  for (int qs = 0; qs < 2; ++qs)
#pragma unroll
    for (int d = 0; d < 4; ++d) oacc[qs][d] = (f32x4){0.f, 0.f, 0.f, 0.f};
  float li[2] = {0.f, 0.f};
  unsigned short* Pw = Pa[wave];

  auto stage = [&](int t, int buf) {
    const char* kbase = Kh + (size_t)t * 8192;
    char* kd = (char*)Ks[buf];
    async16(kbase + tid * 16, kd + tid * 16);
    async16(kbase + 4096 + tid * 16, kd + 4096 + tid * 16);
    const char* vbase = Vh + (size_t)t * 128;
    char* vd = (char*)Vs[buf];
    async16(vbase + (size_t)(tid >> 3) * 2048 + (tid & 7) * 16, vd + tid * 16);
    async16(vbase + (size_t)((tid >> 3) + 32) * 2048 + (tid & 7) * 16, vd + 4096 + tid * 16);
  };

  stage(0, 0);
  for (int t = 0; t < 16; ++t) {
    asm volatile("s_waitcnt vmcnt(0)" ::: "memory");
    __syncthreads();
    if (t < 15) stage(t + 1, (t + 1) & 1);
    const unsigned short* Kst = Ks[t & 1];
    const unsigned short* Vst = Vs[t & 1];

    f32x4 st[4][2];
#pragma unroll
    for (int kt = 0; kt < 4; ++kt) {
      int krow = kt * 16 + lrow;
      int ksw = krow & 7;
      const unsigned short* Kr = Kst + krow * 64;
      bf16x8 k0 = *(const bf16x8*)(Kr + ((qd ^ ksw) << 3));
      bf16x8 k1 = *(const bf16x8*)(Kr + (((qd + 4) ^ ksw) << 3));
#pragma unroll
      for (int qs = 0; qs < 2; ++qs) {
        f32x4 z = (f32x4){0.f, 0.f, 0.f, 0.f};
        z = __builtin_amdgcn_mfma_f32_16x16x32_bf16(k0, qf[qs][0], z, 0, 0, 0);
        z = __builtin_amdgcn_mfma_f32_16x16x32_bf16(k1, qf[qs][1], z, 0, 0, 0);
        st[kt][qs] = z;
      }
    }

#pragma unroll
    for (int kt = 0; kt < 4; ++kt)
#pragma unroll
      for (int qs = 0; qs < 2; ++qs) {
        float p0 = __expf(st[kt][qs][0]);
        float p1 = __expf(st[kt][qs][1]);
        float p2 = __expf(st[kt][qs][2]);
        float p3 = __expf(st[kt][qs][3]);
        li[qs] += (p0 + p1) + (p2 + p3);
        uint2 pk;
        pk.x = (uint32_t)f2b(p0) | ((uint32_t)f2b(p1) << 16);
        pk.y = (uint32_t)f2b(p2) | ((uint32_t)f2b(p3) << 16);
        *(uint2*)(Pw + (qs * 16 + lrow) * PPAD + kt * 16 + qd * 4) = pk;
      }
    asm volatile("s_waitcnt lgkmcnt(0)" ::: "memory");

    bf16x8 ap[2][2];
#pragma unroll
    for (int qs = 0; qs < 2; ++qs)
#pragma unroll
      for (int kh = 0; kh < 2; ++kh)
        ap[qs][kh] = *(const bf16x8*)(Pw + (qs * 16 + lrow) * PPAD + kh * 32 + qd * 8);

#pragma unroll
    for (int ds = 0; ds < 4; ++ds) {
      int vrow = ds * 16 + lrow;
      int vsw = vrow & 7;
      const unsigned short* Vr = Vst + vrow * 64;
      bf16x8 v0 = *(const bf16x8*)(Vr + ((qd ^ vsw) << 3));
      bf16x8 v1 = *(const bf16x8*)(Vr + (((4 + qd) ^ vsw) << 3));
#pragma unroll
      for (int qs = 0; qs < 2; ++qs) {
        oacc[qs][ds] = __builtin_amdgcn_mfma_f32_16x16x32_bf16(ap[qs][0], v0, oacc[qs][ds], 0, 0, 0);
        oacc[qs][ds] = __builtin_amdgcn_mfma_f32_16x16x32_bf16(ap[qs][1], v1, oacc[qs][ds], 0, 0, 0);
      }
    }
  }

#pragma unroll
  for (int qs = 0; qs < 2; ++qs) {
    li[qs] += __shfl_xor(li[qs], 16);
    li[qs] += __shfl_xor(li[qs], 32);
  }

#pragma unroll
  for (int qs = 0; qs < 2; ++qs)
#pragma unroll
    for (int r = 0; r < 4; ++r) {
      float inv = 1.f / __shfl(li[qs], qd * 4 + r);
      int n = qw + qs * 16 + qd * 4 + r;
#pragma unroll
      for (int ds = 0; ds < 4; ++ds) {
        int dh = ds * 16 + lrow;
        o[((size_t)(b * SEQ + n)) * DIM + hh * DH + dh] = f2b(oacc[qs][ds][r] * inv);
      }
    }
}

extern "C" void kernel_launch(void* const* d_in, const int* in_sizes, int n_in,
                              void* d_out, int out_size, void* d_ws, size_t ws_size,
                              hipStream_t stream) {
  const float* x     = (const float*)d_in[0];
  const float* ln1_g = (const float*)d_in[1];
  const float* ln1_b = (const float*)d_in[2];
  const float* w_qkv = (const float*)d_in[3];
  const float* w_out = (const float*)d_in[4];
  const float* b_out = (const float*)d_in[5];
  const float* ln2_g = (const float*)d_in[6];
  const float* ln2_b = (const float*)d_in[7];
  const float* w1    = (const float*)d_in[8];
  const float* b1    = (const float*)d_in[9];
  const float* w2    = (const float*)d_in[10];
  const float* b2    = (const float*)d_in[11];

  char* ws = (char*)d_ws;
  unsigned short* wqkvT = (unsigned short*)(ws + 0);
  unsigned short* woutT = (unsigned short*)(ws + 3538944);
  unsigned short* w1T   = (unsigned short*)(ws + 4718592);
  unsigned short* w2T   = (unsigned short*)(ws + 9437184);
  float*          x2    = (float*)(ws + 14155776);
  unsigned short* h     = (unsigned short*)(ws + 39321600);
  char* big = ws + 51904512;
  unsigned short* Qb = (unsigned short*)(big);
  unsigned short* Kb = (unsigned short*)(big + 12582912);
  unsigned short* Vt = (unsigned short*)(big + 25165824);
  unsigned short* ob = (unsigned short*)(big + 37748736);
  unsigned short* am = (unsigned short*)(big);

  // one launch: 4 weight transposes + ln1 (all independent of each other)
  prep_k<<<8960, 256, 0, stream>>>(w_qkv, w_out, w1, w2, x, ln1_g, ln1_b,
                                   wqkvT, woutT, w1T, w2T, h);
  gemm1b_k<0, 128><<<64 * 18, 256, 0, stream>>>(h, wqkvT, ROWS, 2304, 768,
                                                nullptr, nullptr, nullptr, nullptr, Qb, Kb, Vt);
  attn_k<<<768, 256, 0, stream>>>(Qb, Kb, Vt, ob);
  gemm1b_k<1, 64><<<64 * 12, 256, 0, stream>>>(ob, woutT, ROWS, 768, 768,
                                               b_out, x, x2, nullptr, nullptr, nullptr, nullptr);
  ln_k<<<2048, 256, 0, stream>>>(x2, ln2_g, ln2_b, h);
  gemm1b_k<2, 128><<<64 * 24, 256, 0, stream>>>(h, w1T, ROWS, 3072, 768,
                                                b1, nullptr, nullptr, am, nullptr, nullptr, nullptr);
  gemm1b_k<1, 64><<<64 * 12, 256, 0, stream>>>(am, w2T, ROWS, 768, 3072,
                                               b2, x2, (float*)d_out, nullptr, nullptr, nullptr, nullptr);
}